// Round 16
// baseline (261.819 us; speedup 1.0000x reference)
//
#include <hip/hip_runtime.h>
#include <hip/hip_bf16.h>

// x: (2, 3, 192, 192, 180) fp32 ; windows: 1152 of 192 tokens (3x8x8); heads 6 x 30
#define NWIN 1152

// Output layout (floats): xo (2*192*192*181) | pred_q (1152*64*180) | x_pred (1152*64*180)
#define XO_ELEMS   13344768
#define PRED_ELEMS 13271040

typedef __attribute__((ext_vector_type(8))) short short8v;
typedef __attribute__((ext_vector_type(4))) float f32x4;

__device__ inline short bfbits(float f) {
    __hip_bfloat16 h = __float2bfloat16(f);
    return *reinterpret_cast<short*>(&h);
}

__device__ inline void load_shift(const int* sp, int& s0, int& s1, int& s2) {
    // shift_size may arrive as int32[3] or raw int64[3] (odd slots = high words).
    int v0 = sp[0], v1 = sp[1], v2 = sp[2], v3 = sp[3], v4 = sp[4], v5 = sp[5];
    if (v1 == 0 && v3 == 0 && v5 == 0) { s0 = v0; s1 = v2; s2 = v4; }
    else { s0 = v0; s1 = v1; s2 = v2; }
    s0 = ((s0 % 3) + 3) % 3;
    s1 = ((s1 % 192) + 192) % 192;
    s2 = ((s2 % 192) + 192) % 192;
}

// ---------------------------------------------------------------------------
// kW: one-shot weight conversion to padded bf16.
// ---------------------------------------------------------------------------
__global__ __launch_bounds__(256) void kW(const float* __restrict__ wq,
                                          const float* __restrict__ wp,
                                          short* __restrict__ Wb, short* __restrict__ Wpb) {
    int idx = blockIdx.x * 256 + threadIdx.x;
    if (idx < 576 * 192) {
        int n = idx / 192, k = idx - n * 192;
        Wb[idx] = (n < 540 && k < 180) ? bfbits(wq[n * 180 + k]) : (short)0;
    } else {
        idx -= 576 * 192;
        if (idx < 192 * 192) {
            int n = idx / 192, k = idx - n * 192;
            Wpb[idx] = (n < 180 && k < 180) ? bfbits(wp[n * 180 + k]) : (short)0;
        }
    }
}

// ---------------------------------------------------------------------------
// kA: QKV projection via MFMA (r15 structure) + dead-work elimination:
//  - blocks whose 128 tokens are all < 128 within their window (gbase0%192==0,
//    1/3 of blocks) need NO q output -> start the subtile loop at ns=2.
//  - per-wave: quarters with no q-tokens skip the MFMA/epilogue bodies of the
//    pure-q subtiles ns=0,1 (barriers and W staging untouched).
//  - ns==8 & wm==1 computes only n>=544 (>539, all masked) -> skip body.
// ---------------------------------------------------------------------------
__global__ __launch_bounds__(512, 4) void kA(
    const float* __restrict__ x, const short* __restrict__ Wb, const float* __restrict__ bq,
    const int* __restrict__ shiftp,
    short* __restrict__ qb, short* __restrict__ kb, short* __restrict__ vtb,
    float* __restrict__ predq)
{
    __shared__ short As[128 * 200];  // [tok][k], stride 200
    __shared__ short Ws[64 * 200];   // [n][k]
    __shared__ int rowbase[128];
    int s0, s1, s2; load_shift(shiftp, s0, s1, s2);
    const int tid    = threadIdx.x;
    const int gbase0 = blockIdx.x * 128;   // 1728 blocks

    if (tid < 128) {
        int g = gbase0 + tid;
        int win = g / 192;
        int n = g - win * 192;
        int d = n >> 6;
        int rem = n & 63;
        int i = rem >> 3, j = rem & 7;
        int bb = win / 576;
        int hw = win - bb * 576;
        int hj = hw / 24, wj = hw - hj * 24;
        int t = d + s0; if (t >= 3) t -= 3;
        int ho = hj * 8 + i + s1; if (ho >= 192) ho -= 192;
        int wo = wj * 8 + j + s2; if (wo >= 192) wo -= 192;
        rowbase[tid] = (((bb * 3 + t) * 192 + ho) * 192 + wo) * 180;
    }
    __syncthreads();
    for (int idx = tid; idx < 128 * 45; idx += 512) {
        int r = idx / 45, c4 = idx - r * 45;
        float4 v = *(const float4*)(x + rowbase[r] + c4 * 4);
        int g = gbase0 + r;
        int win = g / 192;
        int ntok = g - win * 192;
        if (ntok >= 128)
            *(float4*)(predq + (win * 64 + ntok - 128) * 180 + c4 * 4) = v;
        short4 sv = make_short4(bfbits(v.x), bfbits(v.y), bfbits(v.z), bfbits(v.w));
        *(short4*)(&As[r * 200 + c4 * 4]) = sv;
    }
    if (tid < 384) {
        int r = tid / 3, p = tid - r * 3;
        *(short4*)(&As[r * 200 + 180 + p * 4]) = make_short4(0, 0, 0, 0);
    }

    const int nsStart = ((gbase0 % 192) == 0) ? 2 : 0;  // block-level q skip

    int wrow[3], wcol[3];
    short8v wreg[3];
    #pragma unroll
    for (int j = 0; j < 3; ++j) {
        int c = tid + j * 512;
        wrow[j] = c / 24;
        wcol[j] = (c - wrow[j] * 24) * 8;
    }
    #pragma unroll
    for (int j = 0; j < 3; ++j)
        wreg[j] = *(const short8v*)(Wb + (nsStart * 64 + wrow[j]) * 192 + wcol[j]);
    #pragma unroll
    for (int j = 0; j < 3; ++j)
        *(short8v*)(&Ws[wrow[j] * 200 + wcol[j]]) = wreg[j];

    const int l    = tid & 63;
    const int w    = tid >> 6;
    const int wm   = w & 1;
    const int wtok = w >> 1;
    const int lr   = l & 15, lg = l >> 4;
    // wave's 32-token quarter never straddles a window boundary:
    const bool waveq = ((gbase0 + wtok * 32) % 192) >= 128;

    __syncthreads();   // As fully staged (Ws[nsStart] also written)
    short8v ta[6], tb[6];
    #pragma unroll
    for (int kk = 0; kk < 6; ++kk) {
        int k0 = kk * 32 + lg * 8;
        ta[kk] = *(const short8v*)(&As[(wtok * 32 + lr) * 200 + k0]);
        tb[kk] = *(const short8v*)(&As[(wtok * 32 + 16 + lr) * 200 + k0]);
    }

    for (int ns = nsStart; ns < 9; ++ns) {
        __syncthreads();
        if (ns < 8) {
            #pragma unroll
            for (int j = 0; j < 3; ++j)
                wreg[j] = *(const short8v*)(Wb + ((ns + 1) * 64 + wrow[j]) * 192 + wcol[j]);
        }
        // ns 0,1 are pure-q subtiles: waves with no q-tokens skip the body.
        // ns==8 & wm==1: all n >= 544 > 539 -> body is dead.
        const bool doBody = ((ns >= 2) || waveq) && !(ns == 8 && wm == 1);
        if (doBody) {
        f32x4 acc[2][2];
        #pragma unroll
        for (int i = 0; i < 2; ++i)
            #pragma unroll
            for (int j = 0; j < 2; ++j) acc[i][j] = (f32x4){0.f, 0.f, 0.f, 0.f};
        #pragma unroll
        for (int kk = 0; kk < 6; ++kk) {
            int k0 = kk * 32 + lg * 8;
            short8v wa0 = *(const short8v*)(&Ws[(wm * 32 + lr) * 200 + k0]);
            short8v wa1 = *(const short8v*)(&Ws[(wm * 32 + 16 + lr) * 200 + k0]);
            acc[0][0] = __builtin_amdgcn_mfma_f32_16x16x32_bf16(wa0, ta[kk], acc[0][0], 0, 0, 0);
            acc[0][1] = __builtin_amdgcn_mfma_f32_16x16x32_bf16(wa0, tb[kk], acc[0][1], 0, 0, 0);
            acc[1][0] = __builtin_amdgcn_mfma_f32_16x16x32_bf16(wa1, ta[kk], acc[1][0], 0, 0, 0);
            acc[1][1] = __builtin_amdgcn_mfma_f32_16x16x32_bf16(wa1, tb[kk], acc[1][1], 0, 0, 0);
        }
        #pragma unroll
        for (int af = 0; af < 2; ++af) {
            int n0 = ns * 64 + wm * 32 + af * 16 + lg * 4;
            if (n0 >= 540) continue;
            float4 bias = *(const float4*)(bq + n0);
            int which = (n0 >= 360) ? 2 : (n0 >= 180) ? 1 : 0;
            int hrem = n0 - which * 180;
            int head = (hrem * 137) >> 12;   // hrem/30, exact for 0..179
            int dd = hrem - head * 30;
            #pragma unroll
            for (int bf = 0; bf < 2; ++bf) {
                int gb = gbase0 + wtok * 32 + bf * 16;
                int win = gb / 192;
                int ntokb = gb - win * 192;
                if (which == 0 && ntokb < 128) continue;
                int ntok = ntokb + lr;
                float v0 = acc[af][bf][0] + bias.x;
                float v1 = acc[af][bf][1] + bias.y;
                float v2 = acc[af][bf][2] + bias.z;
                float v3 = acc[af][bf][3] + bias.w;
                if (which == 2) {
                    short* vh = vtb + (win * 6 + head) * 5760 + ntok;
                    float vr[4] = {v0, v1, v2, v3};
                    #pragma unroll
                    for (int r = 0; r < 4; ++r) {
                        int drow = dd + r;
                        int off = (drow <= 29) ? drow * 192 : (5760 + (drow - 30) * 192);
                        vh[off] = bfbits(vr[r]);
                    }
                } else {
                    short* base;
                    int hstride;
                    if (which == 0) {
                        const float sc = 0.18257418583505536f;  // 30^-0.5
                        v0 *= sc; v1 *= sc; v2 *= sc; v3 *= sc;
                        base = qb + (win * 6 + head) * 1920 + (ntok - 128) * 30 + dd;
                        hstride = 1920;
                    } else {
                        base = kb + (win * 6 + head) * 5760 + ntok * 30 + dd;
                        hstride = 5760;
                    }
                    *(short2*)(base) = make_short2(bfbits(v0), bfbits(v1));
                    short* hi = (dd <= 26) ? (base + 2) : (base + hstride - 28);
                    *(short2*)(hi) = make_short2(bfbits(v2), bfbits(v3));
                }
            }
        }
        }  // doBody
        __syncthreads();
        if (ns < 8) {
            #pragma unroll
            for (int j = 0; j < 3; ++j)
                *(short8v*)(&Ws[wrow[j] * 200 + wcol[j]]) = wreg[j];
        }
    }
}

// ---------------------------------------------------------------------------
// kB: MFMA attention — r10/r15 build verbatim (verified): int4 staging with
// pad-leak trick, K/P LDS overlay, V from the transposed vt buffer.
// ---------------------------------------------------------------------------
__global__ __launch_bounds__(256) void kB(
    const short* __restrict__ qb, const short* __restrict__ kb,
    const short* __restrict__ vt, const float* __restrict__ rpb,
    short* __restrict__ ob)
{
    __shared__ __attribute__((aligned(16))) short Ql[64 * 32];    //  4096 B
    __shared__ __attribute__((aligned(16))) short KP[64 * 200];   // 25600 B: Kl(192x32) then Pl(64x200)
    __shared__ __attribute__((aligned(16))) short Vt[32 * 200];   // 12800 B
    __shared__ float rpbl[675];
    const int blk = blockIdx.x;
    const int win = blk / 6, head = blk - win * 6;
    const int tid = threadIdx.x;

    const short* qsrc = qb + (win * 6 + head) * 1920;
    const short* ksrc = kb + (win * 6 + head) * 5760;
    const short* vsrc = vt + (win * 6 + head) * 5760;

    {
        int row = tid >> 2, q = tid & 3;
        const int* p = (const int*)(qsrc + row * 30 + q * 8);
        int b3 = (q == 3) ? 0 : p[3];
        *(int4*)(&Ql[row * 32 + q * 8]) = make_int4(p[0], p[1], p[2], b3);
    }
    #pragma unroll
    for (int j = 0; j < 3; ++j) {
        int c = tid + j * 256;
        int row = c >> 2, q = c & 3;
        const int* p = (const int*)(ksrc + row * 30 + q * 8);
        *(int4*)(&KP[row * 32 + q * 8]) = make_int4(p[0], p[1], p[2], p[3]);
    }
    #pragma unroll
    for (int j = 0; j < 3; ++j) {
        int c = tid + j * 256;
        if (c < 720) {
            int row = c / 24, col = c - row * 24;
            const int* p = (const int*)(vsrc + c * 8);
            *(int4*)(&Vt[row * 200 + col * 8]) = make_int4(p[0], p[1], p[2], p[3]);
        }
    }
    if (tid < 50) *(short8v*)(&Vt[30 * 200 + tid * 8]) = (short8v){0,0,0,0,0,0,0,0};
    for (int i = tid; i < 675; i += 256) rpbl[i] = rpb[i * 6 + head];
    __syncthreads();

    const int l  = tid & 63;
    const int w  = tid >> 6;
    const int lr = l & 15, lg = l >> 4;
    const int rowbase = w * 16;

    short8v aq = *(const short8v*)(&Ql[(rowbase + lr) * 32 + lg * 8]);
    f32x4 s[12];
    #pragma unroll
    for (int f = 0; f < 12; ++f) {
        short8v b = *(const short8v*)(&KP[(f * 16 + lr) * 32 + lg * 8]);
        s[f] = __builtin_amdgcn_mfma_f32_16x16x32_bf16(aq, b, (f32x4){0.f, 0.f, 0.f, 0.f}, 0, 0, 0);
    }
    __syncthreads();   // K region dead; P may overwrite

    int cr[4];
    #pragma unroll
    for (int r = 0; r < 4; ++r) {
        int qi = rowbase + lg * 4 + r;
        int yi = qi >> 3, xi = qi & 7;
        cr[r] = yi * 15 + xi + 112;
    }
    #pragma unroll
    for (int f = 0; f < 12; ++f) {
        int kc = f * 16 + lr;
        int dk = kc >> 6;
        int rm = kc & 63;
        int yk = rm >> 3, xk = rm & 7;
        int koff = (2 - dk) * 225 - yk * 15 - xk;
        #pragma unroll
        for (int r = 0; r < 4; ++r) s[f][r] += rpbl[cr[r] + koff];
    }
    float m0 = s[0][0], m1 = s[0][1], m2 = s[0][2], m3 = s[0][3];
    #pragma unroll
    for (int f = 1; f < 12; ++f) {
        m0 = fmaxf(m0, s[f][0]); m1 = fmaxf(m1, s[f][1]);
        m2 = fmaxf(m2, s[f][2]); m3 = fmaxf(m3, s[f][3]);
    }
    #pragma unroll
    for (int d = 1; d < 16; d <<= 1) {
        m0 = fmaxf(m0, __shfl_xor(m0, d)); m1 = fmaxf(m1, __shfl_xor(m1, d));
        m2 = fmaxf(m2, __shfl_xor(m2, d)); m3 = fmaxf(m3, __shfl_xor(m3, d));
    }
    float d0 = 0.f, d1 = 0.f, d2 = 0.f, d3 = 0.f;
    #pragma unroll
    for (int f = 0; f < 12; ++f) {
        float p0 = __expf(s[f][0] - m0); d0 += p0;
        float p1 = __expf(s[f][1] - m1); d1 += p1;
        float p2 = __expf(s[f][2] - m2); d2 += p2;
        float p3 = __expf(s[f][3] - m3); d3 += p3;
        int col = f * 16 + lr;
        KP[(rowbase + lg * 4 + 0) * 200 + col] = bfbits(p0);
        KP[(rowbase + lg * 4 + 1) * 200 + col] = bfbits(p1);
        KP[(rowbase + lg * 4 + 2) * 200 + col] = bfbits(p2);
        KP[(rowbase + lg * 4 + 3) * 200 + col] = bfbits(p3);
    }
    #pragma unroll
    for (int d = 1; d < 16; d <<= 1) {
        d0 += __shfl_xor(d0, d); d1 += __shfl_xor(d1, d);
        d2 += __shfl_xor(d2, d); d3 += __shfl_xor(d3, d);
    }
    float inv[4] = {1.f / d0, 1.f / d1, 1.f / d2, 1.f / d3};

    f32x4 o0 = (f32x4){0.f, 0.f, 0.f, 0.f};
    f32x4 o1 = (f32x4){0.f, 0.f, 0.f, 0.f};
    #pragma unroll
    for (int ks = 0; ks < 6; ++ks) {
        int k0 = ks * 32 + lg * 8;
        short8v pa = *(const short8v*)(&KP[(rowbase + lr) * 200 + k0]);
        short8v b0 = *(const short8v*)(&Vt[lr * 200 + k0]);
        short8v b1 = *(const short8v*)(&Vt[(16 + lr) * 200 + k0]);
        o0 = __builtin_amdgcn_mfma_f32_16x16x32_bf16(pa, b0, o0, 0, 0, 0);
        o1 = __builtin_amdgcn_mfma_f32_16x16x32_bf16(pa, b1, o1, 0, 0, 0);
    }
    #pragma unroll
    for (int r = 0; r < 4; ++r) {
        int qi = rowbase + lg * 4 + r;
        short* dst = ob + ((win * 64 + qi) * 6 + head) * 30;
        dst[lr] = bfbits(o0[r] * inv[r]);
        if (lr < 14) dst[16 + lr] = bfbits(o1[r] * inv[r]);
    }
}

// ---------------------------------------------------------------------------
// kC: output projection via MFMA + LDS-staged coalesced outputs (r15 build,
// verified): acc in regs, f32 tile overlay on dead As/Ws, dense stores.
// ---------------------------------------------------------------------------
__global__ __launch_bounds__(256) void kC(
    const short* __restrict__ ob, const short* __restrict__ Wpb, const float* __restrict__ bp,
    const int* __restrict__ shiftp, float* __restrict__ xo, float* __restrict__ xpred)
{
    __shared__ __attribute__((aligned(16))) char smem[51200]; // As | Ws, later f32 tile[64][184]
    __shared__ int rowoff[64];
    short* As = (short*)smem;
    short* Ws = (short*)(smem + 25600);
    float* tile = (float*)smem;

    int s0, s1, s2; load_shift(shiftp, s0, s1, s2);
    const int win = blockIdx.x;
    const int tid = threadIdx.x;
    const int bb = win / 576;
    const int hw = win - bb * 576;
    const int hj = hw / 24, wj = hw - hj * 24;

    if (tid < 64) {
        int i = tid >> 3, j = tid & 7;
        int ho = hj * 8 + i + s1; if (ho >= 192) ho -= 192;
        int wo = wj * 8 + j + s2; if (wo >= 192) wo -= 192;
        rowoff[tid] = ((bb * 192 + ho) * 192 + wo) * 181;
    }

    const short* src = ob + win * 64 * 180;
    for (int idx = tid; idx < 64 * 45; idx += 256) {
        int r = idx / 45, c4 = idx - r * 45;
        *(short4*)(&As[r * 200 + c4 * 4]) = *(const short4*)(src + r * 180 + c4 * 4);
    }
    if (tid < 192) {
        int r = tid / 3, p = tid - r * 3;
        *(short4*)(&As[r * 200 + 180 + p * 4]) = make_short4(0, 0, 0, 0);
    }

    int wrow[6], wcol[6];
    short8v wreg[6];
    #pragma unroll
    for (int j = 0; j < 6; ++j) {
        int c = tid + j * 256;
        wrow[j] = c / 24;
        wcol[j] = (c - wrow[j] * 24) * 8;
    }
    #pragma unroll
    for (int j = 0; j < 6; ++j)
        wreg[j] = *(const short8v*)(Wpb + wrow[j] * 192 + wcol[j]);
    #pragma unroll
    for (int j = 0; j < 6; ++j)
        *(short8v*)(&Ws[wrow[j] * 200 + wcol[j]]) = wreg[j];

    const int l  = tid & 63;
    const int w  = tid >> 6;
    const int wm = w >> 1, wn = w & 1;
    const int lr = l & 15, lg = l >> 4;

    f32x4 acc3[3][2][2];
    #pragma unroll
    for (int ns = 0; ns < 3; ++ns) {
        __syncthreads();
        if (ns < 2) {
            #pragma unroll
            for (int j = 0; j < 6; ++j)
                wreg[j] = *(const short8v*)(Wpb + ((ns + 1) * 64 + wrow[j]) * 192 + wcol[j]);
        }
        #pragma unroll
        for (int i = 0; i < 2; ++i)
            #pragma unroll
            for (int j = 0; j < 2; ++j) acc3[ns][i][j] = (f32x4){0.f, 0.f, 0.f, 0.f};
        #pragma unroll
        for (int kk = 0; kk < 6; ++kk) {
            int k0 = kk * 32 + lg * 8;
            short8v wa0 = *(const short8v*)(&Ws[(wm * 32 + lr) * 200 + k0]);
            short8v wa1 = *(const short8v*)(&Ws[(wm * 32 + 16 + lr) * 200 + k0]);
            short8v tb0 = *(const short8v*)(&As[(wn * 32 + lr) * 200 + k0]);
            short8v tb1 = *(const short8v*)(&As[(wn * 32 + 16 + lr) * 200 + k0]);
            acc3[ns][0][0] = __builtin_amdgcn_mfma_f32_16x16x32_bf16(wa0, tb0, acc3[ns][0][0], 0, 0, 0);
            acc3[ns][0][1] = __builtin_amdgcn_mfma_f32_16x16x32_bf16(wa0, tb1, acc3[ns][0][1], 0, 0, 0);
            acc3[ns][1][0] = __builtin_amdgcn_mfma_f32_16x16x32_bf16(wa1, tb0, acc3[ns][1][0], 0, 0, 0);
            acc3[ns][1][1] = __builtin_amdgcn_mfma_f32_16x16x32_bf16(wa1, tb1, acc3[ns][1][1], 0, 0, 0);
        }
        __syncthreads();
        if (ns < 2) {
            #pragma unroll
            for (int j = 0; j < 6; ++j)
                *(short8v*)(&Ws[wrow[j] * 200 + wcol[j]]) = wreg[j];
        }
    }
    #pragma unroll
    for (int ns = 0; ns < 3; ++ns) {
        #pragma unroll
        for (int af = 0; af < 2; ++af) {
            int n0 = ns * 64 + wm * 32 + af * 16 + lg * 4;
            if (n0 >= 180) continue;
            float4 bias = *(const float4*)(bp + n0);
            #pragma unroll
            for (int bf = 0; bf < 2; ++bf) {
                int qi = wn * 32 + bf * 16 + lr;
                float4 v = make_float4(acc3[ns][af][bf][0] + bias.x,
                                       acc3[ns][af][bf][1] + bias.y,
                                       acc3[ns][af][bf][2] + bias.z,
                                       acc3[ns][af][bf][3] + bias.w);
                *(float4*)(&tile[qi * 184 + n0]) = v;
            }
        }
    }
    if (tid < 64) tile[tid * 184 + 180] = 1.0f;
    __syncthreads();

    float* prow = xpred + win * 64 * 180;
    for (int idx = tid; idx < 64 * 45; idx += 256) {
        int r = idx / 45, c4 = idx - r * 45;
        *(float4*)(prow + r * 180 + c4 * 4) = *(const float4*)(&tile[r * 184 + c4 * 4]);
    }
    for (int idx = tid; idx < 64 * 181; idx += 256) {
        int r = idx / 181, n = idx - r * 181;
        xo[rowoff[r] + n] = tile[r * 184 + n];
    }
}

// ---------------------------------------------------------------------------
extern "C" void kernel_launch(void* const* d_in, const int* in_sizes, int n_in,
                              void* d_out, int out_size, void* d_ws, size_t ws_size,
                              hipStream_t stream) {
    const float* x      = (const float*)d_in[0];
    const float* w_qkv  = (const float*)d_in[1];
    const float* b_qkv  = (const float*)d_in[2];
    const float* w_proj = (const float*)d_in[3];
    const float* b_proj = (const float*)d_in[4];
    const float* rpb    = (const float*)d_in[5];
    const int*   shiftp = (const int*)d_in[6];

    float* out    = (float*)d_out;
    float* xo     = out;
    float* pred_q = out + XO_ELEMS;
    float* x_pred = out + XO_ELEMS + PRED_ELEMS;

    // ws layout (bytes): Wb 221184 | Wpb 73728 | qb 26542080 | kb 79626240 | vt 79626240 | ob 26542080
    char* ws = (char*)d_ws;
    short* Wb  = (short*)(ws);
    short* Wpb = (short*)(ws + 221184);
    short* qb  = (short*)(ws + 294912);
    short* kb  = (short*)(ws + 294912 + 26542080);
    short* vtb = (short*)(ws + 294912 + 26542080 + 79626240);
    short* ob  = (short*)(ws + 294912 + 26542080 + 79626240 + 79626240);
    // total: 212,631,552 bytes (unchanged)

    hipLaunchKernelGGL(kW, dim3(576), dim3(256), 0, stream, w_qkv, w_proj, Wb, Wpb);
    hipLaunchKernelGGL(kA, dim3(1728), dim3(512), 0, stream, x, Wb, b_qkv, shiftp, qb, kb, vtb, pred_q);
    hipLaunchKernelGGL(kB, dim3(NWIN * 6), dim3(256), 0, stream, qb, kb, vtb, rpb, ob);
    hipLaunchKernelGGL(kC, dim3(NWIN), dim3(256), 0, stream, ob, Wpb, b_proj, shiftp, xo, x_pred);
}

// Round 17
// 253.713 us; speedup vs baseline: 1.0320x; 1.0320x over previous
//
#include <hip/hip_runtime.h>
#include <hip/hip_bf16.h>

// x: (2, 3, 192, 192, 180) fp32 ; windows: 1152 of 192 tokens (3x8x8); heads 6 x 30
#define NWIN 1152

// Output layout (floats): xo (2*192*192*181) | pred_q (1152*64*180) | x_pred (1152*64*180)
#define XO_ELEMS   13344768
#define PRED_ELEMS 13271040

typedef __attribute__((ext_vector_type(8))) short short8v;
typedef __attribute__((ext_vector_type(4))) float f32x4;

__device__ inline short bfbits(float f) {
    __hip_bfloat16 h = __float2bfloat16(f);
    return *reinterpret_cast<short*>(&h);
}

__device__ inline void load_shift(const int* sp, int& s0, int& s1, int& s2) {
    // shift_size may arrive as int32[3] or raw int64[3] (odd slots = high words).
    int v0 = sp[0], v1 = sp[1], v2 = sp[2], v3 = sp[3], v4 = sp[4], v5 = sp[5];
    if (v1 == 0 && v3 == 0 && v5 == 0) { s0 = v0; s1 = v2; s2 = v4; }
    else { s0 = v0; s1 = v1; s2 = v2; }
    s0 = ((s0 % 3) + 3) % 3;
    s1 = ((s1 % 192) + 192) % 192;
    s2 = ((s2 % 192) + 192) % 192;
}

// ---------------------------------------------------------------------------
// kW: one-shot weight conversion to padded bf16.
// ---------------------------------------------------------------------------
__global__ __launch_bounds__(256) void kW(const float* __restrict__ wq,
                                          const float* __restrict__ wp,
                                          short* __restrict__ Wb, short* __restrict__ Wpb) {
    int idx = blockIdx.x * 256 + threadIdx.x;
    if (idx < 576 * 192) {
        int n = idx / 192, k = idx - n * 192;
        Wb[idx] = (n < 540 && k < 180) ? bfbits(wq[n * 180 + k]) : (short)0;
    } else {
        idx -= 576 * 192;
        if (idx < 192 * 192) {
            int n = idx / 192, k = idx - n * 192;
            Wpb[idx] = (n < 180 && k < 180) ? bfbits(wp[n * 180 + k]) : (short)0;
        }
    }
}

// ---------------------------------------------------------------------------
// kA: QKV projection via MFMA — r10/r15 build verbatim (verified, ~167 us):
// 512 threads, two 64-token tiles, Ws staged via reg prefetch, hoisted token
// fragments. Outputs: q/k tok-major stride-30, v transposed [head][dd][tok].
// ---------------------------------------------------------------------------
__global__ __launch_bounds__(512, 4) void kA(
    const float* __restrict__ x, const short* __restrict__ Wb, const float* __restrict__ bq,
    const int* __restrict__ shiftp,
    short* __restrict__ qb, short* __restrict__ kb, short* __restrict__ vtb,
    float* __restrict__ predq)
{
    __shared__ short As[128 * 200];  // [tok][k], stride 200
    __shared__ short Ws[64 * 200];   // [n][k]
    __shared__ int rowbase[128];
    int s0, s1, s2; load_shift(shiftp, s0, s1, s2);
    const int tid    = threadIdx.x;
    const int gbase0 = blockIdx.x * 128;   // 1728 blocks

    if (tid < 128) {
        int g = gbase0 + tid;
        int win = g / 192;
        int n = g - win * 192;
        int d = n >> 6;
        int rem = n & 63;
        int i = rem >> 3, j = rem & 7;
        int bb = win / 576;
        int hw = win - bb * 576;
        int hj = hw / 24, wj = hw - hj * 24;
        int t = d + s0; if (t >= 3) t -= 3;
        int ho = hj * 8 + i + s1; if (ho >= 192) ho -= 192;
        int wo = wj * 8 + j + s2; if (wo >= 192) wo -= 192;
        rowbase[tid] = (((bb * 3 + t) * 192 + ho) * 192 + wo) * 180;
    }
    __syncthreads();
    for (int idx = tid; idx < 128 * 45; idx += 512) {
        int r = idx / 45, c4 = idx - r * 45;
        float4 v = *(const float4*)(x + rowbase[r] + c4 * 4);
        int g = gbase0 + r;
        int win = g / 192;
        int ntok = g - win * 192;
        if (ntok >= 128)
            *(float4*)(predq + (win * 64 + ntok - 128) * 180 + c4 * 4) = v;
        short4 sv = make_short4(bfbits(v.x), bfbits(v.y), bfbits(v.z), bfbits(v.w));
        *(short4*)(&As[r * 200 + c4 * 4]) = sv;
    }
    if (tid < 384) {
        int r = tid / 3, p = tid - r * 3;
        *(short4*)(&As[r * 200 + 180 + p * 4]) = make_short4(0, 0, 0, 0);
    }

    int wrow[3], wcol[3];
    short8v wreg[3];
    #pragma unroll
    for (int j = 0; j < 3; ++j) {
        int c = tid + j * 512;
        wrow[j] = c / 24;
        wcol[j] = (c - wrow[j] * 24) * 8;
    }
    #pragma unroll
    for (int j = 0; j < 3; ++j)
        wreg[j] = *(const short8v*)(Wb + wrow[j] * 192 + wcol[j]);
    #pragma unroll
    for (int j = 0; j < 3; ++j)
        *(short8v*)(&Ws[wrow[j] * 200 + wcol[j]]) = wreg[j];

    const int l    = tid & 63;
    const int w    = tid >> 6;
    const int wm   = w & 1;
    const int wtok = w >> 1;
    const int lr   = l & 15, lg = l >> 4;

    __syncthreads();   // As fully staged (Ws0 also written)
    short8v ta[6], tb[6];
    #pragma unroll
    for (int kk = 0; kk < 6; ++kk) {
        int k0 = kk * 32 + lg * 8;
        ta[kk] = *(const short8v*)(&As[(wtok * 32 + lr) * 200 + k0]);
        tb[kk] = *(const short8v*)(&As[(wtok * 32 + 16 + lr) * 200 + k0]);
    }

    for (int ns = 0; ns < 9; ++ns) {
        __syncthreads();
        if (ns < 8) {
            #pragma unroll
            for (int j = 0; j < 3; ++j)
                wreg[j] = *(const short8v*)(Wb + ((ns + 1) * 64 + wrow[j]) * 192 + wcol[j]);
        }
        f32x4 acc[2][2];
        #pragma unroll
        for (int i = 0; i < 2; ++i)
            #pragma unroll
            for (int j = 0; j < 2; ++j) acc[i][j] = (f32x4){0.f, 0.f, 0.f, 0.f};
        #pragma unroll
        for (int kk = 0; kk < 6; ++kk) {
            int k0 = kk * 32 + lg * 8;
            short8v wa0 = *(const short8v*)(&Ws[(wm * 32 + lr) * 200 + k0]);
            short8v wa1 = *(const short8v*)(&Ws[(wm * 32 + 16 + lr) * 200 + k0]);
            acc[0][0] = __builtin_amdgcn_mfma_f32_16x16x32_bf16(wa0, ta[kk], acc[0][0], 0, 0, 0);
            acc[0][1] = __builtin_amdgcn_mfma_f32_16x16x32_bf16(wa0, tb[kk], acc[0][1], 0, 0, 0);
            acc[1][0] = __builtin_amdgcn_mfma_f32_16x16x32_bf16(wa1, ta[kk], acc[1][0], 0, 0, 0);
            acc[1][1] = __builtin_amdgcn_mfma_f32_16x16x32_bf16(wa1, tb[kk], acc[1][1], 0, 0, 0);
        }
        #pragma unroll
        for (int af = 0; af < 2; ++af) {
            int n0 = ns * 64 + wm * 32 + af * 16 + lg * 4;
            if (n0 >= 540) continue;
            float4 bias = *(const float4*)(bq + n0);
            int which = (n0 >= 360) ? 2 : (n0 >= 180) ? 1 : 0;
            int hrem = n0 - which * 180;
            int head = (hrem * 137) >> 12;   // hrem/30, exact for 0..179
            int dd = hrem - head * 30;
            #pragma unroll
            for (int bf = 0; bf < 2; ++bf) {
                int gb = gbase0 + wtok * 32 + bf * 16;
                int win = gb / 192;
                int ntokb = gb - win * 192;
                if (which == 0 && ntokb < 128) continue;
                int ntok = ntokb + lr;
                float v0 = acc[af][bf][0] + bias.x;
                float v1 = acc[af][bf][1] + bias.y;
                float v2 = acc[af][bf][2] + bias.z;
                float v3 = acc[af][bf][3] + bias.w;
                if (which == 2) {
                    short* vh = vtb + (win * 6 + head) * 5760 + ntok;
                    float vr[4] = {v0, v1, v2, v3};
                    #pragma unroll
                    for (int r = 0; r < 4; ++r) {
                        int drow = dd + r;
                        int off = (drow <= 29) ? drow * 192 : (5760 + (drow - 30) * 192);
                        vh[off] = bfbits(vr[r]);
                    }
                } else {
                    short* base;
                    int hstride;
                    if (which == 0) {
                        const float sc = 0.18257418583505536f;  // 30^-0.5
                        v0 *= sc; v1 *= sc; v2 *= sc; v3 *= sc;
                        base = qb + (win * 6 + head) * 1920 + (ntok - 128) * 30 + dd;
                        hstride = 1920;
                    } else {
                        base = kb + (win * 6 + head) * 5760 + ntok * 30 + dd;
                        hstride = 5760;
                    }
                    *(short2*)(base) = make_short2(bfbits(v0), bfbits(v1));
                    short* hi = (dd <= 26) ? (base + 2) : (base + hstride - 28);
                    *(short2*)(hi) = make_short2(bfbits(v2), bfbits(v3));
                }
            }
        }
        __syncthreads();
        if (ns < 8) {
            #pragma unroll
            for (int j = 0; j < 3; ++j)
                *(short8v*)(&Ws[wrow[j] * 200 + wcol[j]]) = wreg[j];
        }
    }
}

// ---------------------------------------------------------------------------
// kB: MFMA attention — r10/r15 build verbatim (verified): int4 staging with
// pad-leak trick, K/P LDS overlay, V from the transposed vt buffer.
// ---------------------------------------------------------------------------
__global__ __launch_bounds__(256) void kB(
    const short* __restrict__ qb, const short* __restrict__ kb,
    const short* __restrict__ vt, const float* __restrict__ rpb,
    short* __restrict__ ob)
{
    __shared__ __attribute__((aligned(16))) short Ql[64 * 32];    //  4096 B
    __shared__ __attribute__((aligned(16))) short KP[64 * 200];   // 25600 B: Kl(192x32) then Pl(64x200)
    __shared__ __attribute__((aligned(16))) short Vt[32 * 200];   // 12800 B
    __shared__ float rpbl[675];
    const int blk = blockIdx.x;
    const int win = blk / 6, head = blk - win * 6;
    const int tid = threadIdx.x;

    const short* qsrc = qb + (win * 6 + head) * 1920;
    const short* ksrc = kb + (win * 6 + head) * 5760;
    const short* vsrc = vt + (win * 6 + head) * 5760;

    {
        int row = tid >> 2, q = tid & 3;
        const int* p = (const int*)(qsrc + row * 30 + q * 8);
        int b3 = (q == 3) ? 0 : p[3];
        *(int4*)(&Ql[row * 32 + q * 8]) = make_int4(p[0], p[1], p[2], b3);
    }
    #pragma unroll
    for (int j = 0; j < 3; ++j) {
        int c = tid + j * 256;
        int row = c >> 2, q = c & 3;
        const int* p = (const int*)(ksrc + row * 30 + q * 8);
        *(int4*)(&KP[row * 32 + q * 8]) = make_int4(p[0], p[1], p[2], p[3]);
    }
    #pragma unroll
    for (int j = 0; j < 3; ++j) {
        int c = tid + j * 256;
        if (c < 720) {
            int row = c / 24, col = c - row * 24;
            const int* p = (const int*)(vsrc + c * 8);
            *(int4*)(&Vt[row * 200 + col * 8]) = make_int4(p[0], p[1], p[2], p[3]);
        }
    }
    if (tid < 50) *(short8v*)(&Vt[30 * 200 + tid * 8]) = (short8v){0,0,0,0,0,0,0,0};
    for (int i = tid; i < 675; i += 256) rpbl[i] = rpb[i * 6 + head];
    __syncthreads();

    const int l  = tid & 63;
    const int w  = tid >> 6;
    const int lr = l & 15, lg = l >> 4;
    const int rowbase = w * 16;

    short8v aq = *(const short8v*)(&Ql[(rowbase + lr) * 32 + lg * 8]);
    f32x4 s[12];
    #pragma unroll
    for (int f = 0; f < 12; ++f) {
        short8v b = *(const short8v*)(&KP[(f * 16 + lr) * 32 + lg * 8]);
        s[f] = __builtin_amdgcn_mfma_f32_16x16x32_bf16(aq, b, (f32x4){0.f, 0.f, 0.f, 0.f}, 0, 0, 0);
    }
    __syncthreads();   // K region dead; P may overwrite

    int cr[4];
    #pragma unroll
    for (int r = 0; r < 4; ++r) {
        int qi = rowbase + lg * 4 + r;
        int yi = qi >> 3, xi = qi & 7;
        cr[r] = yi * 15 + xi + 112;
    }
    #pragma unroll
    for (int f = 0; f < 12; ++f) {
        int kc = f * 16 + lr;
        int dk = kc >> 6;
        int rm = kc & 63;
        int yk = rm >> 3, xk = rm & 7;
        int koff = (2 - dk) * 225 - yk * 15 - xk;
        #pragma unroll
        for (int r = 0; r < 4; ++r) s[f][r] += rpbl[cr[r] + koff];
    }
    float m0 = s[0][0], m1 = s[0][1], m2 = s[0][2], m3 = s[0][3];
    #pragma unroll
    for (int f = 1; f < 12; ++f) {
        m0 = fmaxf(m0, s[f][0]); m1 = fmaxf(m1, s[f][1]);
        m2 = fmaxf(m2, s[f][2]); m3 = fmaxf(m3, s[f][3]);
    }
    #pragma unroll
    for (int d = 1; d < 16; d <<= 1) {
        m0 = fmaxf(m0, __shfl_xor(m0, d)); m1 = fmaxf(m1, __shfl_xor(m1, d));
        m2 = fmaxf(m2, __shfl_xor(m2, d)); m3 = fmaxf(m3, __shfl_xor(m3, d));
    }
    float d0 = 0.f, d1 = 0.f, d2 = 0.f, d3 = 0.f;
    #pragma unroll
    for (int f = 0; f < 12; ++f) {
        float p0 = __expf(s[f][0] - m0); d0 += p0;
        float p1 = __expf(s[f][1] - m1); d1 += p1;
        float p2 = __expf(s[f][2] - m2); d2 += p2;
        float p3 = __expf(s[f][3] - m3); d3 += p3;
        int col = f * 16 + lr;
        KP[(rowbase + lg * 4 + 0) * 200 + col] = bfbits(p0);
        KP[(rowbase + lg * 4 + 1) * 200 + col] = bfbits(p1);
        KP[(rowbase + lg * 4 + 2) * 200 + col] = bfbits(p2);
        KP[(rowbase + lg * 4 + 3) * 200 + col] = bfbits(p3);
    }
    #pragma unroll
    for (int d = 1; d < 16; d <<= 1) {
        d0 += __shfl_xor(d0, d); d1 += __shfl_xor(d1, d);
        d2 += __shfl_xor(d2, d); d3 += __shfl_xor(d3, d);
    }
    float inv[4] = {1.f / d0, 1.f / d1, 1.f / d2, 1.f / d3};

    f32x4 o0 = (f32x4){0.f, 0.f, 0.f, 0.f};
    f32x4 o1 = (f32x4){0.f, 0.f, 0.f, 0.f};
    #pragma unroll
    for (int ks = 0; ks < 6; ++ks) {
        int k0 = ks * 32 + lg * 8;
        short8v pa = *(const short8v*)(&KP[(rowbase + lr) * 200 + k0]);
        short8v b0 = *(const short8v*)(&Vt[lr * 200 + k0]);
        short8v b1 = *(const short8v*)(&Vt[(16 + lr) * 200 + k0]);
        o0 = __builtin_amdgcn_mfma_f32_16x16x32_bf16(pa, b0, o0, 0, 0, 0);
        o1 = __builtin_amdgcn_mfma_f32_16x16x32_bf16(pa, b1, o1, 0, 0, 0);
    }
    #pragma unroll
    for (int r = 0; r < 4; ++r) {
        int qi = rowbase + lg * 4 + r;
        short* dst = ob + ((win * 64 + qi) * 6 + head) * 30;
        dst[lr] = bfbits(o0[r] * inv[r]);
        if (lr < 14) dst[16 + lr] = bfbits(o1[r] * inv[r]);
    }
}

// ---------------------------------------------------------------------------
// kC: output projection via MFMA + LDS-staged coalesced outputs (r15 build,
// verified): acc in regs, f32 tile overlay on dead As/Ws, dense stores.
// ---------------------------------------------------------------------------
__global__ __launch_bounds__(256) void kC(
    const short* __restrict__ ob, const short* __restrict__ Wpb, const float* __restrict__ bp,
    const int* __restrict__ shiftp, float* __restrict__ xo, float* __restrict__ xpred)
{
    __shared__ __attribute__((aligned(16))) char smem[51200]; // As | Ws, later f32 tile[64][184]
    __shared__ int rowoff[64];
    short* As = (short*)smem;
    short* Ws = (short*)(smem + 25600);
    float* tile = (float*)smem;

    int s0, s1, s2; load_shift(shiftp, s0, s1, s2);
    const int win = blockIdx.x;
    const int tid = threadIdx.x;
    const int bb = win / 576;
    const int hw = win - bb * 576;
    const int hj = hw / 24, wj = hw - hj * 24;

    if (tid < 64) {
        int i = tid >> 3, j = tid & 7;
        int ho = hj * 8 + i + s1; if (ho >= 192) ho -= 192;
        int wo = wj * 8 + j + s2; if (wo >= 192) wo -= 192;
        rowoff[tid] = ((bb * 192 + ho) * 192 + wo) * 181;
    }

    const short* src = ob + win * 64 * 180;
    for (int idx = tid; idx < 64 * 45; idx += 256) {
        int r = idx / 45, c4 = idx - r * 45;
        *(short4*)(&As[r * 200 + c4 * 4]) = *(const short4*)(src + r * 180 + c4 * 4);
    }
    if (tid < 192) {
        int r = tid / 3, p = tid - r * 3;
        *(short4*)(&As[r * 200 + 180 + p * 4]) = make_short4(0, 0, 0, 0);
    }

    int wrow[6], wcol[6];
    short8v wreg[6];
    #pragma unroll
    for (int j = 0; j < 6; ++j) {
        int c = tid + j * 256;
        wrow[j] = c / 24;
        wcol[j] = (c - wrow[j] * 24) * 8;
    }
    #pragma unroll
    for (int j = 0; j < 6; ++j)
        wreg[j] = *(const short8v*)(Wpb + wrow[j] * 192 + wcol[j]);
    #pragma unroll
    for (int j = 0; j < 6; ++j)
        *(short8v*)(&Ws[wrow[j] * 200 + wcol[j]]) = wreg[j];

    const int l  = tid & 63;
    const int w  = tid >> 6;
    const int wm = w >> 1, wn = w & 1;
    const int lr = l & 15, lg = l >> 4;

    f32x4 acc3[3][2][2];
    #pragma unroll
    for (int ns = 0; ns < 3; ++ns) {
        __syncthreads();
        if (ns < 2) {
            #pragma unroll
            for (int j = 0; j < 6; ++j)
                wreg[j] = *(const short8v*)(Wpb + ((ns + 1) * 64 + wrow[j]) * 192 + wcol[j]);
        }
        #pragma unroll
        for (int i = 0; i < 2; ++i)
            #pragma unroll
            for (int j = 0; j < 2; ++j) acc3[ns][i][j] = (f32x4){0.f, 0.f, 0.f, 0.f};
        #pragma unroll
        for (int kk = 0; kk < 6; ++kk) {
            int k0 = kk * 32 + lg * 8;
            short8v wa0 = *(const short8v*)(&Ws[(wm * 32 + lr) * 200 + k0]);
            short8v wa1 = *(const short8v*)(&Ws[(wm * 32 + 16 + lr) * 200 + k0]);
            short8v tb0 = *(const short8v*)(&As[(wn * 32 + lr) * 200 + k0]);
            short8v tb1 = *(const short8v*)(&As[(wn * 32 + 16 + lr) * 200 + k0]);
            acc3[ns][0][0] = __builtin_amdgcn_mfma_f32_16x16x32_bf16(wa0, tb0, acc3[ns][0][0], 0, 0, 0);
            acc3[ns][0][1] = __builtin_amdgcn_mfma_f32_16x16x32_bf16(wa0, tb1, acc3[ns][0][1], 0, 0, 0);
            acc3[ns][1][0] = __builtin_amdgcn_mfma_f32_16x16x32_bf16(wa1, tb0, acc3[ns][1][0], 0, 0, 0);
            acc3[ns][1][1] = __builtin_amdgcn_mfma_f32_16x16x32_bf16(wa1, tb1, acc3[ns][1][1], 0, 0, 0);
        }
        __syncthreads();
        if (ns < 2) {
            #pragma unroll
            for (int j = 0; j < 6; ++j)
                *(short8v*)(&Ws[wrow[j] * 200 + wcol[j]]) = wreg[j];
        }
    }
    #pragma unroll
    for (int ns = 0; ns < 3; ++ns) {
        #pragma unroll
        for (int af = 0; af < 2; ++af) {
            int n0 = ns * 64 + wm * 32 + af * 16 + lg * 4;
            if (n0 >= 180) continue;
            float4 bias = *(const float4*)(bp + n0);
            #pragma unroll
            for (int bf = 0; bf < 2; ++bf) {
                int qi = wn * 32 + bf * 16 + lr;
                float4 v = make_float4(acc3[ns][af][bf][0] + bias.x,
                                       acc3[ns][af][bf][1] + bias.y,
                                       acc3[ns][af][bf][2] + bias.z,
                                       acc3[ns][af][bf][3] + bias.w);
                *(float4*)(&tile[qi * 184 + n0]) = v;
            }
        }
    }
    if (tid < 64) tile[tid * 184 + 180] = 1.0f;
    __syncthreads();

    float* prow = xpred + win * 64 * 180;
    for (int idx = tid; idx < 64 * 45; idx += 256) {
        int r = idx / 45, c4 = idx - r * 45;
        *(float4*)(prow + r * 180 + c4 * 4) = *(const float4*)(&tile[r * 184 + c4 * 4]);
    }
    for (int idx = tid; idx < 64 * 181; idx += 256) {
        int r = idx / 181, n = idx - r * 181;
        xo[rowoff[r] + n] = tile[r * 184 + n];
    }
}

// ---------------------------------------------------------------------------
extern "C" void kernel_launch(void* const* d_in, const int* in_sizes, int n_in,
                              void* d_out, int out_size, void* d_ws, size_t ws_size,
                              hipStream_t stream) {
    const float* x      = (const float*)d_in[0];
    const float* w_qkv  = (const float*)d_in[1];
    const float* b_qkv  = (const float*)d_in[2];
    const float* w_proj = (const float*)d_in[3];
    const float* b_proj = (const float*)d_in[4];
    const float* rpb    = (const float*)d_in[5];
    const int*   shiftp = (const int*)d_in[6];

    float* out    = (float*)d_out;
    float* xo     = out;
    float* pred_q = out + XO_ELEMS;
    float* x_pred = out + XO_ELEMS + PRED_ELEMS;

    // ws layout (bytes): Wb 221184 | Wpb 73728 | qb 26542080 | kb 79626240 | vt 79626240 | ob 26542080
    char* ws = (char*)d_ws;
    short* Wb  = (short*)(ws);
    short* Wpb = (short*)(ws + 221184);
    short* qb  = (short*)(ws + 294912);
    short* kb  = (short*)(ws + 294912 + 26542080);
    short* vtb = (short*)(ws + 294912 + 26542080 + 79626240);
    short* ob  = (short*)(ws + 294912 + 26542080 + 79626240 + 79626240);
    // total: 212,631,552 bytes (unchanged)

    hipLaunchKernelGGL(kW, dim3(576), dim3(256), 0, stream, w_qkv, w_proj, Wb, Wpb);
    hipLaunchKernelGGL(kA, dim3(1728), dim3(512), 0, stream, x, Wb, b_qkv, shiftp, qb, kb, vtb, pred_q);
    hipLaunchKernelGGL(kB, dim3(NWIN * 6), dim3(256), 0, stream, qb, kb, vtb, rpb, ob);
    hipLaunchKernelGGL(kC, dim3(NWIN), dim3(256), 0, stream, ob, Wpb, b_proj, shiftp, xo, x_pred);
}